// Round 1
// baseline (449.092 us; speedup 1.0000x reference)
//
#include <hip/hip_runtime.h>
#include <hip/hip_bf16.h>

// Problem constants (from reference)
#define HID 256
#define H1H 8
#define C1 32
#define C2 16
#define NEG 0.2f

__device__ __forceinline__ float lrelu(float t){ return (t >= 0.f) ? t : NEG * t; }

// ---------------- GEMM1: h1 = relu(x) @ W1   [M,256] x [256,256] ----------------
__global__ __launch_bounds__(256) void gemm1_k(const float* __restrict__ X,
                                               const float* __restrict__ W,
                                               float* __restrict__ H1o, int M)
{
    __shared__ float As[16][68];
    __shared__ float Bs[16][68];
    int bm = blockIdx.x * 64, bn = blockIdx.y * 64;
    int tid = threadIdx.x;
    int tx = tid & 15, ty = tid >> 4;
    float acc[4][4] = {};
    for (int k0 = 0; k0 < 256; k0 += 16) {
        #pragma unroll
        for (int i = 0; i < 4; i++) {
            int idx = tid + (i << 8);
            int k = idx & 15, mm = idx >> 4;
            int gm = bm + mm;
            float v = 0.f;
            if (gm < M) v = X[(long)gm * 256 + k0 + k];
            As[k][mm] = fmaxf(v, 0.f);           // fused relu(x)
            int nn = idx & 63, kk = idx >> 6;
            Bs[kk][nn] = W[(long)(k0 + kk) * 256 + bn + nn];
        }
        __syncthreads();
        #pragma unroll
        for (int k = 0; k < 16; k++) {
            float a[4], b[4];
            #pragma unroll
            for (int i = 0; i < 4; i++) a[i] = As[k][(ty << 2) + i];
            #pragma unroll
            for (int j = 0; j < 4; j++) b[j] = Bs[k][(tx << 2) + j];
            #pragma unroll
            for (int i = 0; i < 4; i++)
                #pragma unroll
                for (int j = 0; j < 4; j++) acc[i][j] += a[i] * b[j];
        }
        __syncthreads();
    }
    #pragma unroll
    for (int i = 0; i < 4; i++) {
        int gm = bm + (ty << 2) + i;
        if (gm < M) {
            #pragma unroll
            for (int j = 0; j < 4; j++)
                H1o[(long)gm * 256 + bn + (tx << 2) + j] = acc[i][j];
        }
    }
}

// ---------------- alpha1: per (n,h) dot of h1 row with a_src/a_dst ----------------
__global__ __launch_bounds__(256) void alpha1_k(const float* __restrict__ H1,
                                                const float* __restrict__ a1s,
                                                const float* __restrict__ a1d,
                                                float* __restrict__ as1,
                                                float* __restrict__ ad1, int Nn)
{
    int i = blockIdx.x * 256 + threadIdx.x;
    if (i >= Nn * H1H) return;
    int h = i & 7;
    const float4* row = (const float4*)(H1 + (long)i * C1);
    const float4* av  = (const float4*)(a1s + h * C1);
    const float4* dv  = (const float4*)(a1d + h * C1);
    float ss = 0.f, sd = 0.f;
    #pragma unroll
    for (int q = 0; q < 8; q++) {
        float4 v = row[q], a = av[q], d = dv[q];
        ss += v.x*a.x + v.y*a.y + v.z*a.z + v.w*a.w;
        sd += v.x*d.x + v.y*d.y + v.z*d.z + v.w*d.w;
    }
    as1[i] = ss; ad1[i] = sd;
}

// ---------------- CSR build ----------------
__global__ void deg_init_k(int* deg, int Nn)
{
    int i = blockIdx.x * 256 + threadIdx.x;
    if (i < Nn) deg[i] = 1;  // self loop
}
__global__ void deg_count_k(const int* __restrict__ dst, int E, int* deg)
{
    int i = blockIdx.x * 256 + threadIdx.x;
    if (i < E) atomicAdd(&deg[dst[i]], 1);
}
// block-level inclusive scan: 1024 elems / block (256 thr x 4)
__global__ __launch_bounds__(256) void scan1_k(const int* __restrict__ deg,
                                               int* __restrict__ incl,
                                               int* __restrict__ bsum, int Nn)
{
    __shared__ int sh[256];
    int t = threadIdx.x;
    int base = blockIdx.x * 1024 + t * 4;
    int v0 = (base     < Nn) ? deg[base]     : 0;
    int v1 = (base + 1 < Nn) ? deg[base + 1] : 0;
    int v2 = (base + 2 < Nn) ? deg[base + 2] : 0;
    int v3 = (base + 3 < Nn) ? deg[base + 3] : 0;
    int s0 = v0, s1 = s0 + v1, s2 = s1 + v2, s3 = s2 + v3;
    sh[t] = s3;
    __syncthreads();
    for (int off = 1; off < 256; off <<= 1) {
        int x = (t >= off) ? sh[t - off] : 0;
        __syncthreads();
        sh[t] += x;
        __syncthreads();
    }
    int prev = (t > 0) ? sh[t - 1] : 0;
    if (base     < Nn) incl[base]     = prev + s0;
    if (base + 1 < Nn) incl[base + 1] = prev + s1;
    if (base + 2 < Nn) incl[base + 2] = prev + s2;
    if (base + 3 < Nn) incl[base + 3] = prev + s3;
    if (t == 255) bsum[blockIdx.x] = sh[255];
}
__global__ void scan2_k(const int* __restrict__ bsum, int* __restrict__ bpre, int nb)
{
    int t = threadIdx.x;                // single wave of 64, nb <= 64
    int own = (t < nb) ? bsum[t] : 0;
    int v = own;
    for (int off = 1; off < 64; off <<= 1) {
        int x = __shfl_up(v, off);
        if (t >= off) v += x;
    }
    if (t < nb) bpre[t] = v - own;      // exclusive
}
__global__ void scan3_k(const int* __restrict__ incl, const int* __restrict__ deg,
                        const int* __restrict__ bpre, int* __restrict__ offs,
                        int* __restrict__ cursor, int Nn, int Etot)
{
    int i = blockIdx.x * 256 + threadIdx.x;
    if (i < Nn) {
        int e = bpre[i >> 10] + incl[i] - deg[i];
        offs[i] = e;
        cursor[i] = e;
    }
    if (i == 0) offs[Nn] = Etot;
}
__global__ void scatter_k(const int* __restrict__ src, const int* __restrict__ dst,
                          int E, int Nn, int* cursor, int* __restrict__ srcs)
{
    int i = blockIdx.x * 256 + threadIdx.x;
    if (i < E) {
        int p = atomicAdd(&cursor[dst[i]], 1);
        srcs[p] = src[i];
    } else if (i < E + Nn) {
        int n = i - E;
        int p = atomicAdd(&cursor[n], 1);
        srcs[p] = n;                    // self loop
    }
}

// ---------------- GAT layer 1 aggregate: wave per dst node ----------------
__global__ __launch_bounds__(256) void gat1_agg_k(const float* __restrict__ H1,
    const float* __restrict__ as1, const float* __restrict__ ad1,
    const int* __restrict__ offs, const int* __restrict__ srcs,
    const float* __restrict__ b1, float* __restrict__ X1, int Nn)
{
    int w = (blockIdx.x << 2) + (threadIdx.x >> 6);
    if (w >= Nn) return;
    int lane = threadIdx.x & 63;
    int he = lane & 7, el = lane >> 3;
    int beg = offs[w], end = offs[w + 1];
    float adv = ad1[(w << 3) + he];
    // pass 1: per-head max
    float m = -1e30f;
    for (int j0 = beg; j0 < end; j0 += 8) {
        int j = j0 + el;
        float e = -1e30f;
        if (j < end) {
            int s = srcs[j];
            e = lrelu(as1[(s << 3) + he] + adv);
        }
        m = fmaxf(m, e);
    }
    m = fmaxf(m, __shfl_xor(m, 8));
    m = fmaxf(m, __shfl_xor(m, 16));
    m = fmaxf(m, __shfl_xor(m, 32));
    // pass 2: per-head denom
    float dsum = 0.f;
    for (int j0 = beg; j0 < end; j0 += 8) {
        int j = j0 + el;
        if (j < end) {
            int s = srcs[j];
            dsum += __expf(lrelu(as1[(s << 3) + he] + adv) - m);
        }
    }
    dsum += __shfl_xor(dsum, 8);
    dsum += __shfl_xor(dsum, 16);
    dsum += __shfl_xor(dsum, 32);
    float inv = 1.f / dsum;
    // pass 3: weighted gather-accumulate (4 floats per lane = 256 per wave)
    float acc0 = 0.f, acc1 = 0.f, acc2 = 0.f, acc3 = 0.f;
    int hk = lane >> 5;  // head low bit selector for k blocks
    for (int j0 = beg; j0 < end; j0 += 8) {
        int j = j0 + el;
        int s = 0; float wv = 0.f;
        if (j < end) {
            s = srcs[j];
            wv = __expf(lrelu(as1[(s << 3) + he] + adv) - m) * inv;
        }
        int ne = min(end - j0, 8);
        for (int e8 = 0; e8 < ne; e8++) {
            int sb = __shfl(s, e8 << 3);
            float w0 = __shfl(wv, (e8 << 3) + 0 + hk);
            float w1 = __shfl(wv, (e8 << 3) + 2 + hk);
            float w2 = __shfl(wv, (e8 << 3) + 4 + hk);
            float w3 = __shfl(wv, (e8 << 3) + 6 + hk);
            const float* hr = H1 + ((long)sb << 8);
            acc0 += w0 * hr[lane];
            acc1 += w1 * hr[lane + 64];
            acc2 += w2 * hr[lane + 128];
            acc3 += w3 * hr[lane + 192];
        }
    }
    float* xr = X1 + ((long)w << 8);
    xr[lane]       = fmaxf(acc0 + b1[lane],       0.f);
    xr[lane + 64]  = fmaxf(acc1 + b1[lane + 64],  0.f);
    xr[lane + 128] = fmaxf(acc2 + b1[lane + 128], 0.f);
    xr[lane + 192] = fmaxf(acc3 + b1[lane + 192], 0.f);
}

// ---------------- GEMM2 + alpha2: h2 = x1 @ W2, wave per node ----------------
__global__ __launch_bounds__(256) void gemm2_k(const float* __restrict__ X1,
    const float* __restrict__ W2, const float* __restrict__ a2s_w,
    const float* __restrict__ a2d_w, float* __restrict__ H2,
    float* __restrict__ as2, float* __restrict__ ad2, int Nn)
{
    __shared__ float Ws[256 * 16];
    for (int i = threadIdx.x; i < 256 * 16; i += 256) Ws[i] = W2[i];
    __syncthreads();
    int w = (blockIdx.x << 2) + (threadIdx.x >> 6);
    if (w >= Nn) return;
    int lane = threadIdx.x & 63;
    int c = lane & 15, kg = lane >> 4;
    const float* xr = X1 + ((long)w << 8);
    float sum = 0.f;
    for (int t = 0; t < 64; t++) {
        int k = (t << 2) + kg;
        sum += xr[k] * Ws[(k << 4) + c];
    }
    sum += __shfl_xor(sum, 16);
    sum += __shfl_xor(sum, 32);
    float vs = sum * a2s_w[c];
    float vd = sum * a2d_w[c];
    for (int off = 1; off < 16; off <<= 1) {
        vs += __shfl_xor(vs, off);
        vd += __shfl_xor(vd, off);
    }
    if (kg == 0) {
        H2[(w << 4) + c] = sum;
        if (c == 0) { as2[w] = vs; ad2[w] = vd; }
    }
}

// ---------------- GAT layer 2 aggregate + final softmax ----------------
__global__ __launch_bounds__(256) void gat2_agg_k(const float* __restrict__ H2,
    const float* __restrict__ as2, const float* __restrict__ ad2,
    const int* __restrict__ offs, const int* __restrict__ srcs,
    const float* __restrict__ b2, float* __restrict__ out, int Nn)
{
    int w = (blockIdx.x << 2) + (threadIdx.x >> 6);
    if (w >= Nn) return;
    int lane = threadIdx.x & 63;
    int beg = offs[w], end = offs[w + 1];
    float adv = ad2[w];
    float m = -1e30f;
    for (int j = beg + lane; j < end; j += 64)
        m = fmaxf(m, lrelu(as2[srcs[j]] + adv));
    for (int off = 32; off; off >>= 1) m = fmaxf(m, __shfl_xor(m, off));
    float ds = 0.f;
    for (int j = beg + lane; j < end; j += 64)
        ds += __expf(lrelu(as2[srcs[j]] + adv) - m);
    for (int off = 32; off; off >>= 1) ds += __shfl_xor(ds, off);
    float inv = 1.f / ds;
    int c = lane & 15, eg = lane >> 4;
    float acc = 0.f;
    for (int j0 = beg; j0 < end; j0 += 4) {
        int j = j0 + eg;
        if (j < end) {
            int s = srcs[j];
            float wv = __expf(lrelu(as2[s] + adv) - m) * inv;
            acc += wv * H2[(s << 4) + c];
        }
    }
    acc += __shfl_xor(acc, 16);
    acc += __shfl_xor(acc, 32);
    float v = acc + b2[c];
    float mx = v;
    for (int off = 1; off < 16; off <<= 1) mx = fmaxf(mx, __shfl_xor(mx, off));
    float ex = __expf(v - mx);
    float se = ex;
    for (int off = 1; off < 16; off <<= 1) se += __shfl_xor(se, off);
    if (eg == 0) out[(w << 4) + c] = ex / se;
}

// ---------------- host launcher ----------------
extern "C" void kernel_launch(void* const* d_in, const int* in_sizes, int n_in,
                              void* d_out, int out_size, void* d_ws, size_t ws_size,
                              hipStream_t stream)
{
    const float* x    = (const float*)d_in[0];
    const int*   ei   = (const int*)d_in[1];
    const float* W1   = (const float*)d_in[2];
    const float* a1s  = (const float*)d_in[3];
    const float* a1d  = (const float*)d_in[4];
    const float* b1   = (const float*)d_in[5];
    const float* W2   = (const float*)d_in[6];
    const float* a2s  = (const float*)d_in[7];
    const float* a2d  = (const float*)d_in[8];
    const float* b2   = (const float*)d_in[9];
    float* out = (float*)d_out;

    int N = in_sizes[0] / HID;
    int E = in_sizes[1] / 2;
    int Etot = E + N;
    const int* src = ei;
    const int* dst = ei + E;

    // workspace layout
    char* p = (char*)d_ws;
    auto alloc = [&](size_t bytes) {
        void* r = (void*)p;
        p += (bytes + 255) & ~(size_t)255;
        return r;
    };
    float* h1     = (float*)alloc((size_t)N * 256 * 4);
    float* x1     = (float*)alloc((size_t)N * 256 * 4);
    float* h2     = (float*)alloc((size_t)N * 16 * 4);
    float* as1    = (float*)alloc((size_t)N * 8 * 4);
    float* ad1    = (float*)alloc((size_t)N * 8 * 4);
    float* as2v   = (float*)alloc((size_t)N * 4);
    float* ad2v   = (float*)alloc((size_t)N * 4);
    int*   deg    = (int*)alloc((size_t)N * 4);
    int*   incl   = (int*)alloc((size_t)N * 4);
    int*   offs   = (int*)alloc((size_t)(N + 1) * 4);
    int*   cursor = (int*)alloc((size_t)N * 4);
    int*   bsum   = (int*)alloc(256 * 4);
    int*   bpre   = (int*)alloc(256 * 4);
    int*   srcs   = (int*)alloc((size_t)Etot * 4);

    int nb = (N + 1023) / 1024;

    // GEMM1 + alphas
    dim3 g1((N + 63) / 64, 4);
    hipLaunchKernelGGL(gemm1_k, g1, dim3(256), 0, stream, x, W1, h1, N);
    hipLaunchKernelGGL(alpha1_k, dim3((N * 8 + 255) / 256), dim3(256), 0, stream,
                       h1, a1s, a1d, as1, ad1, N);
    // CSR build
    hipLaunchKernelGGL(deg_init_k, dim3((N + 255) / 256), dim3(256), 0, stream, deg, N);
    hipLaunchKernelGGL(deg_count_k, dim3((E + 255) / 256), dim3(256), 0, stream, dst, E, deg);
    hipLaunchKernelGGL(scan1_k, dim3(nb), dim3(256), 0, stream, deg, incl, bsum, N);
    hipLaunchKernelGGL(scan2_k, dim3(1), dim3(64), 0, stream, bsum, bpre, nb);
    hipLaunchKernelGGL(scan3_k, dim3((N + 255) / 256), dim3(256), 0, stream,
                       incl, deg, bpre, offs, cursor, N, Etot);
    hipLaunchKernelGGL(scatter_k, dim3((Etot + 255) / 256), dim3(256), 0, stream,
                       src, dst, E, N, cursor, srcs);
    // layer 1 aggregate
    hipLaunchKernelGGL(gat1_agg_k, dim3((N + 3) / 4), dim3(256), 0, stream,
                       h1, as1, ad1, offs, srcs, b1, x1, N);
    // layer 2
    hipLaunchKernelGGL(gemm2_k, dim3((N + 3) / 4), dim3(256), 0, stream,
                       x1, W2, a2s, a2d, h2, as2v, ad2v, N);
    hipLaunchKernelGGL(gat2_agg_k, dim3((N + 3) / 4), dim3(256), 0, stream,
                       h2, as2v, ad2v, offs, srcs, b2, out, N);
}

// Round 2
// 435.708 us; speedup vs baseline: 1.0307x; 1.0307x over previous
//
#include <hip/hip_runtime.h>
#include <hip/hip_bf16.h>

#define HID 256
#define H1H 8
#define C1 32
#define C2 16
#define NEG 0.2f

__device__ __forceinline__ float lrelu(float t){ return (t >= 0.f) ? t : NEG * t; }

// ---------------- GEMM1: h1 = relu(x) @ W1  + fused alpha1 dots ----------------
// grid: (4 col-tiles, rowTiles) -- col fastest so sibling blocks share the X tile
__global__ __launch_bounds__(256) void gemm1_k(const float* __restrict__ X,
                                               const float* __restrict__ W,
                                               const float* __restrict__ a1s_g,
                                               const float* __restrict__ a1d_g,
                                               float* __restrict__ H1o,
                                               float* __restrict__ as1,
                                               float* __restrict__ ad1, int M)
{
    __shared__ float As[16][68];
    __shared__ float Bs[16][68];
    int bm = blockIdx.y * 64, bn = blockIdx.x * 64;
    int tid = threadIdx.x;
    int tx = tid & 15, ty = tid >> 4;
    float acc[4][4] = {};
    for (int k0 = 0; k0 < 256; k0 += 16) {
        {   // staging: float4 loads
            int mm = tid >> 2, kq = tid & 3;       // X: 64 rows x 16 k
            int gm = bm + mm;
            float4 xv = {0.f,0.f,0.f,0.f};
            if (gm < M) xv = *(const float4*)(X + (long)gm * 256 + k0 + (kq << 2));
            As[(kq << 2) + 0][mm] = fmaxf(xv.x, 0.f);
            As[(kq << 2) + 1][mm] = fmaxf(xv.y, 0.f);
            As[(kq << 2) + 2][mm] = fmaxf(xv.z, 0.f);
            As[(kq << 2) + 3][mm] = fmaxf(xv.w, 0.f);
            int kk = tid >> 4, nq = tid & 15;      // W: 16 k x 64 n
            float4 wv = *(const float4*)(W + (long)(k0 + kk) * 256 + bn + (nq << 2));
            *(float4*)&Bs[kk][nq << 2] = wv;
        }
        __syncthreads();
        #pragma unroll
        for (int k = 0; k < 16; k++) {
            float4 a4 = *(const float4*)&As[k][ty << 2];
            float4 b4 = *(const float4*)&Bs[k][tx << 2];
            float a[4] = {a4.x, a4.y, a4.z, a4.w};
            float b[4] = {b4.x, b4.y, b4.z, b4.w};
            #pragma unroll
            for (int i = 0; i < 4; i++)
                #pragma unroll
                for (int j = 0; j < 4; j++) acc[i][j] += a[i] * b[j];
        }
        __syncthreads();
    }
    // fused alpha dots: this thread's 4 cols all live in head hb
    int hb = (bn >> 5) + (tx >> 3);
    int cb = (tx & 7) << 2;
    float av[4], dv[4];
    #pragma unroll
    for (int j = 0; j < 4; j++) {
        av[j] = a1s_g[(hb << 5) + cb + j];
        dv[j] = a1d_g[(hb << 5) + cb + j];
    }
    float ps[4] = {}, pd[4] = {};
    #pragma unroll
    for (int i = 0; i < 4; i++)
        #pragma unroll
        for (int j = 0; j < 4; j++) {
            ps[i] += acc[i][j] * av[j];
            pd[i] += acc[i][j] * dv[j];
        }
    #pragma unroll
    for (int off = 1; off < 8; off <<= 1) {
        #pragma unroll
        for (int i = 0; i < 4; i++) {
            ps[i] += __shfl_xor(ps[i], off);
            pd[i] += __shfl_xor(pd[i], off);
        }
    }
    #pragma unroll
    for (int i = 0; i < 4; i++) {
        int gm = bm + (ty << 2) + i;
        if (gm < M) {
            float4 o = {acc[i][0], acc[i][1], acc[i][2], acc[i][3]};
            *(float4*)(H1o + (long)gm * 256 + bn + (tx << 2)) = o;
            if ((tx & 7) == 0) {
                as1[(gm << 3) + hb] = ps[i];
                ad1[(gm << 3) + hb] = pd[i];
            }
        }
    }
}

// ---------------- CSR build ----------------
__global__ void deg_init_k(int* deg, int Nn)
{
    int i = blockIdx.x * 256 + threadIdx.x;
    if (i < Nn) deg[i] = 1;  // self loop
}
__global__ void deg_count_k(const int* __restrict__ dst, int E, int* deg)
{
    int i = blockIdx.x * 256 + threadIdx.x;
    if (i < E) atomicAdd(&deg[dst[i]], 1);
}
__global__ __launch_bounds__(256) void scan1_k(const int* __restrict__ deg,
                                               int* __restrict__ incl,
                                               int* __restrict__ bsum, int Nn)
{
    __shared__ int sh[256];
    int t = threadIdx.x;
    int base = blockIdx.x * 1024 + t * 4;
    int v0 = (base     < Nn) ? deg[base]     : 0;
    int v1 = (base + 1 < Nn) ? deg[base + 1] : 0;
    int v2 = (base + 2 < Nn) ? deg[base + 2] : 0;
    int v3 = (base + 3 < Nn) ? deg[base + 3] : 0;
    int s0 = v0, s1 = s0 + v1, s2 = s1 + v2, s3 = s2 + v3;
    sh[t] = s3;
    __syncthreads();
    for (int off = 1; off < 256; off <<= 1) {
        int x = (t >= off) ? sh[t - off] : 0;
        __syncthreads();
        sh[t] += x;
        __syncthreads();
    }
    int prev = (t > 0) ? sh[t - 1] : 0;
    if (base     < Nn) incl[base]     = prev + s0;
    if (base + 1 < Nn) incl[base + 1] = prev + s1;
    if (base + 2 < Nn) incl[base + 2] = prev + s2;
    if (base + 3 < Nn) incl[base + 3] = prev + s3;
    if (t == 255) bsum[blockIdx.x] = sh[255];
}
__global__ void scan2_k(const int* __restrict__ bsum, int* __restrict__ bpre, int nb)
{
    int t = threadIdx.x;                // single wave, nb <= 64
    int own = (t < nb) ? bsum[t] : 0;
    int v = own;
    for (int off = 1; off < 64; off <<= 1) {
        int x = __shfl_up(v, off);
        if (t >= off) v += x;
    }
    if (t < nb) bpre[t] = v - own;      // exclusive
}
__global__ void scan3_k(const int* __restrict__ incl, const int* __restrict__ deg,
                        const int* __restrict__ bpre, int* __restrict__ offs,
                        int* __restrict__ cursor, int Nn, int Etot)
{
    int i = blockIdx.x * 256 + threadIdx.x;
    if (i < Nn) {
        int e = bpre[i >> 10] + incl[i] - deg[i];
        offs[i] = e;
        cursor[i] = e;
    }
    if (i == 0) offs[Nn] = Etot;
}
__global__ void scatter_k(const int* __restrict__ src, const int* __restrict__ dst,
                          int E, int Nn, int* cursor, int* __restrict__ srcs)
{
    int i = blockIdx.x * 256 + threadIdx.x;
    if (i < E) {
        int p = atomicAdd(&cursor[dst[i]], 1);
        srcs[p] = src[i];
    } else if (i < E + Nn) {
        int n = i - E;
        int p = atomicAdd(&cursor[n], 1);
        srcs[p] = n;                    // self loop
    }
}

// ---------------- GAT layer 1 aggregate: wave per dst node ----------------
__global__ __launch_bounds__(256) void gat1_agg_k(const float* __restrict__ H1,
    const float* __restrict__ as1, const float* __restrict__ ad1,
    const int* __restrict__ offs, const int* __restrict__ srcs,
    const float* __restrict__ b1, float* __restrict__ X1, int Nn)
{
    int w = (blockIdx.x << 2) + (threadIdx.x >> 6);
    if (w >= Nn) return;
    int lane = threadIdx.x & 63;
    int he = lane & 7, el = lane >> 3;
    int beg = offs[w], end = offs[w + 1];
    float adv = ad1[(w << 3) + he];
    // pass 1: online softmax (max + denom in one sweep)
    float m = -1e30f, d = 0.f;
    for (int j0 = beg; j0 < end; j0 += 8) {
        int j = j0 + el;
        if (j < end) {
            int s = srcs[j];
            float e = lrelu(as1[(s << 3) + he] + adv);
            float nm = fmaxf(m, e);
            d = d * __expf(m - nm) + __expf(e - nm);
            m = nm;
        }
    }
    #pragma unroll
    for (int off = 8; off < 64; off <<= 1) {
        float mo = __shfl_xor(m, off);
        float dd = __shfl_xor(d, off);
        float nm = fmaxf(m, mo);
        d = d * __expf(m - nm) + dd * __expf(mo - nm);
        m = nm;
    }
    float inv = 1.f / d;
    // pass 2: weighted float4 gather-accumulate
    float4 acc = {0.f, 0.f, 0.f, 0.f};
    int myh = lane >> 3;    // head owning this lane's 4 channels
    for (int j0 = beg; j0 < end; j0 += 8) {
        int j = j0 + el;
        int s = 0; float wv = 0.f;
        if (j < end) {
            s = srcs[j];
            wv = __expf(lrelu(as1[(s << 3) + he] + adv) - m) * inv;
        }
        int ne = min(end - j0, 8);
        int sb[8]; float wb[8];
        #pragma unroll
        for (int e8 = 0; e8 < 8; e8++) {
            sb[e8] = __shfl(s, e8 << 3);
            wb[e8] = __shfl(wv, (e8 << 3) + myh);
        }
        #pragma unroll
        for (int e8 = 0; e8 < 8; e8++) {
            if (e8 < ne) {
                float4 v = ((const float4*)(H1 + ((long)sb[e8] << 8)))[lane];
                acc.x += wb[e8] * v.x;
                acc.y += wb[e8] * v.y;
                acc.z += wb[e8] * v.z;
                acc.w += wb[e8] * v.w;
            }
        }
    }
    float4 bb = ((const float4*)b1)[lane];
    float4 o;
    o.x = fmaxf(acc.x + bb.x, 0.f);
    o.y = fmaxf(acc.y + bb.y, 0.f);
    o.z = fmaxf(acc.z + bb.z, 0.f);
    o.w = fmaxf(acc.w + bb.w, 0.f);
    ((float4*)(X1 + ((long)w << 8)))[lane] = o;
}

// ---------------- GEMM2 + alpha2: h2 = x1 @ W2, wave per node ----------------
__global__ __launch_bounds__(256) void gemm2_k(const float* __restrict__ X1,
    const float* __restrict__ W2, const float* __restrict__ a2s_w,
    const float* __restrict__ a2d_w, float* __restrict__ H2,
    float* __restrict__ as2, float* __restrict__ ad2, int Nn)
{
    __shared__ float Wt[16 * 256];   // transposed: Wt[c][k]
    for (int i = threadIdx.x; i < 16 * 256; i += 256) {
        int c = i >> 8, k = i & 255;
        Wt[i] = W2[(k << 4) + c];
    }
    __syncthreads();
    int w = (blockIdx.x << 2) + (threadIdx.x >> 6);
    if (w >= Nn) return;
    int lane = threadIdx.x & 63;
    int c = lane & 15, kg = lane >> 4;
    const float4* xr4 = (const float4*)(X1 + ((long)w << 8));
    const float* wr = Wt + (c << 8);
    float sum = 0.f;
    #pragma unroll
    for (int t = 0; t < 16; t++) {
        float4 v = xr4[(t << 2) + kg];
        int k = (t << 4) + (kg << 2);
        sum += v.x * wr[k] + v.y * wr[k + 1] + v.z * wr[k + 2] + v.w * wr[k + 3];
    }
    sum += __shfl_xor(sum, 16);
    sum += __shfl_xor(sum, 32);
    float vs = sum * a2s_w[c];
    float vd = sum * a2d_w[c];
    #pragma unroll
    for (int off = 1; off < 16; off <<= 1) {
        vs += __shfl_xor(vs, off);
        vd += __shfl_xor(vd, off);
    }
    if (kg == 0) {
        H2[(w << 4) + c] = sum;
        if (c == 0) { as2[w] = vs; ad2[w] = vd; }
    }
}

// ---------------- GAT layer 2 aggregate + final softmax ----------------
__global__ __launch_bounds__(256) void gat2_agg_k(const float* __restrict__ H2,
    const float* __restrict__ as2, const float* __restrict__ ad2,
    const int* __restrict__ offs, const int* __restrict__ srcs,
    const float* __restrict__ b2, float* __restrict__ out, int Nn)
{
    int w = (blockIdx.x << 2) + (threadIdx.x >> 6);
    if (w >= Nn) return;
    int lane = threadIdx.x & 63;
    int beg = offs[w], end = offs[w + 1];
    float adv = ad2[w];
    // online max+denom
    float m = -1e30f, d = 0.f;
    for (int j = beg + lane; j < end; j += 64) {
        float e = lrelu(as2[srcs[j]] + adv);
        float nm = fmaxf(m, e);
        d = d * __expf(m - nm) + __expf(e - nm);
        m = nm;
    }
    #pragma unroll
    for (int off = 1; off < 64; off <<= 1) {
        float mo = __shfl_xor(m, off);
        float dd = __shfl_xor(d, off);
        float nm = fmaxf(m, mo);
        d = d * __expf(m - nm) + dd * __expf(mo - nm);
        m = nm;
    }
    float inv = 1.f / d;
    int c = lane & 15, eg = lane >> 4;
    float acc = 0.f;
    for (int j0 = beg; j0 < end; j0 += 4) {
        int j = j0 + eg;
        if (j < end) {
            int s = srcs[j];
            float wv = __expf(lrelu(as2[s] + adv) - m) * inv;
            acc += wv * H2[(s << 4) + c];
        }
    }
    acc += __shfl_xor(acc, 16);
    acc += __shfl_xor(acc, 32);
    float v = acc + b2[c];
    float mx = v;
    #pragma unroll
    for (int off = 1; off < 16; off <<= 1) mx = fmaxf(mx, __shfl_xor(mx, off));
    float ex = __expf(v - mx);
    float se = ex;
    #pragma unroll
    for (int off = 1; off < 16; off <<= 1) se += __shfl_xor(se, off);
    if (eg == 0) out[(w << 4) + c] = ex / se;
}

// ---------------- host launcher ----------------
extern "C" void kernel_launch(void* const* d_in, const int* in_sizes, int n_in,
                              void* d_out, int out_size, void* d_ws, size_t ws_size,
                              hipStream_t stream)
{
    const float* x    = (const float*)d_in[0];
    const int*   ei   = (const int*)d_in[1];
    const float* W1   = (const float*)d_in[2];
    const float* a1s  = (const float*)d_in[3];
    const float* a1d  = (const float*)d_in[4];
    const float* b1   = (const float*)d_in[5];
    const float* W2   = (const float*)d_in[6];
    const float* a2s  = (const float*)d_in[7];
    const float* a2d  = (const float*)d_in[8];
    const float* b2   = (const float*)d_in[9];
    float* out = (float*)d_out;

    int N = in_sizes[0] / HID;
    int E = in_sizes[1] / 2;
    int Etot = E + N;
    const int* src = ei;
    const int* dst = ei + E;

    char* p = (char*)d_ws;
    auto alloc = [&](size_t bytes) {
        void* r = (void*)p;
        p += (bytes + 255) & ~(size_t)255;
        return r;
    };
    float* h1     = (float*)alloc((size_t)N * 256 * 4);
    float* x1     = (float*)alloc((size_t)N * 256 * 4);
    float* h2     = (float*)alloc((size_t)N * 16 * 4);
    float* as1    = (float*)alloc((size_t)N * 8 * 4);
    float* ad1    = (float*)alloc((size_t)N * 8 * 4);
    float* as2v   = (float*)alloc((size_t)N * 4);
    float* ad2v   = (float*)alloc((size_t)N * 4);
    int*   deg    = (int*)alloc((size_t)N * 4);
    int*   incl   = (int*)alloc((size_t)N * 4);
    int*   offs   = (int*)alloc((size_t)(N + 1) * 4);
    int*   cursor = (int*)alloc((size_t)N * 4);
    int*   bsum   = (int*)alloc(256 * 4);
    int*   bpre   = (int*)alloc(256 * 4);
    int*   srcs   = (int*)alloc((size_t)Etot * 4);

    int nb = (N + 1023) / 1024;

    // GEMM1 (+ fused alpha1): col-tile fastest for X-tile L2/L3 reuse
    dim3 g1(4, (N + 63) / 64);
    hipLaunchKernelGGL(gemm1_k, g1, dim3(256), 0, stream,
                       x, W1, a1s, a1d, h1, as1, ad1, N);
    // CSR build
    hipLaunchKernelGGL(deg_init_k, dim3((N + 255) / 256), dim3(256), 0, stream, deg, N);
    hipLaunchKernelGGL(deg_count_k, dim3((E + 255) / 256), dim3(256), 0, stream, dst, E, deg);
    hipLaunchKernelGGL(scan1_k, dim3(nb), dim3(256), 0, stream, deg, incl, bsum, N);
    hipLaunchKernelGGL(scan2_k, dim3(1), dim3(64), 0, stream, bsum, bpre, nb);
    hipLaunchKernelGGL(scan3_k, dim3((N + 255) / 256), dim3(256), 0, stream,
                       incl, deg, bpre, offs, cursor, N, Etot);
    hipLaunchKernelGGL(scatter_k, dim3((Etot + 255) / 256), dim3(256), 0, stream,
                       src, dst, E, N, cursor, srcs);
    // layer 1 aggregate
    hipLaunchKernelGGL(gat1_agg_k, dim3((N + 3) / 4), dim3(256), 0, stream,
                       h1, as1, ad1, offs, srcs, b1, x1, N);
    // layer 2
    hipLaunchKernelGGL(gemm2_k, dim3((N + 3) / 4), dim3(256), 0, stream,
                       x1, W2, a2s, a2d, h2, as2v, ad2v, N);
    hipLaunchKernelGGL(gat2_agg_k, dim3((N + 3) / 4), dim3(256), 0, stream,
                       h2, as2v, ad2v, offs, srcs, b2, out, N);
}

// Round 3
// 377.416 us; speedup vs baseline: 1.1899x; 1.1545x over previous
//
#include <hip/hip_runtime.h>
#include <hip/hip_bf16.h>

#define HID 256
#define H1H 8
#define C1 32
#define C2 16
#define NEG 0.2f

typedef unsigned short ushort_t;
typedef unsigned int uint_t;

__device__ __forceinline__ float lrelu(float t){ return (t >= 0.f) ? t : NEG * t; }
__device__ __forceinline__ ushort_t f2bf(float f){
    uint_t u = __float_as_uint(f);
    u = (u + 0x7fffu + ((u >> 16) & 1u)) >> 16;   // RNE
    return (ushort_t)u;
}
__device__ __forceinline__ float bf_lo(uint_t p){ return __uint_as_float(p << 16); }
__device__ __forceinline__ float bf_hi(uint_t p){ return __uint_as_float(p & 0xffff0000u); }

// ---------------- GEMM1: h1 = relu(x) @ W1 (bf16 out) + fused alpha1 dots ----------------
__global__ __launch_bounds__(256) void gemm1_k(const float* __restrict__ X,
                                               const float* __restrict__ W,
                                               const float* __restrict__ a1s_g,
                                               const float* __restrict__ a1d_g,
                                               ushort_t* __restrict__ H1b,
                                               float* __restrict__ as1,
                                               float* __restrict__ ad1, int M)
{
    __shared__ float As[16][68];
    __shared__ float Bs[16][68];
    int bm = blockIdx.y * 64, bn = blockIdx.x * 64;
    int tid = threadIdx.x;
    int tx = tid & 15, ty = tid >> 4;
    float acc[4][4] = {};
    for (int k0 = 0; k0 < 256; k0 += 16) {
        {   // staging: float4 loads
            int mm = tid >> 2, kq = tid & 3;       // X: 64 rows x 16 k
            int gm = bm + mm;
            float4 xv = {0.f,0.f,0.f,0.f};
            if (gm < M) xv = *(const float4*)(X + (long)gm * 256 + k0 + (kq << 2));
            As[(kq << 2) + 0][mm] = fmaxf(xv.x, 0.f);
            As[(kq << 2) + 1][mm] = fmaxf(xv.y, 0.f);
            As[(kq << 2) + 2][mm] = fmaxf(xv.z, 0.f);
            As[(kq << 2) + 3][mm] = fmaxf(xv.w, 0.f);
            int kk = tid >> 4, nq = tid & 15;      // W: 16 k x 64 n
            float4 wv = *(const float4*)(W + (long)(k0 + kk) * 256 + bn + (nq << 2));
            *(float4*)&Bs[kk][nq << 2] = wv;
        }
        __syncthreads();
        #pragma unroll
        for (int k = 0; k < 16; k++) {
            float4 a4 = *(const float4*)&As[k][ty << 2];
            float4 b4 = *(const float4*)&Bs[k][tx << 2];
            float a[4] = {a4.x, a4.y, a4.z, a4.w};
            float b[4] = {b4.x, b4.y, b4.z, b4.w};
            #pragma unroll
            for (int i = 0; i < 4; i++)
                #pragma unroll
                for (int j = 0; j < 4; j++) acc[i][j] += a[i] * b[j];
        }
        __syncthreads();
    }
    // fused alpha dots (fp32): this thread's 4 cols all live in head hb
    int hb = (bn >> 5) + (tx >> 3);
    int cb = (tx & 7) << 2;
    float av[4], dv[4];
    #pragma unroll
    for (int j = 0; j < 4; j++) {
        av[j] = a1s_g[(hb << 5) + cb + j];
        dv[j] = a1d_g[(hb << 5) + cb + j];
    }
    float ps[4] = {}, pd[4] = {};
    #pragma unroll
    for (int i = 0; i < 4; i++)
        #pragma unroll
        for (int j = 0; j < 4; j++) {
            ps[i] += acc[i][j] * av[j];
            pd[i] += acc[i][j] * dv[j];
        }
    #pragma unroll
    for (int off = 1; off < 8; off <<= 1) {
        #pragma unroll
        for (int i = 0; i < 4; i++) {
            ps[i] += __shfl_xor(ps[i], off);
            pd[i] += __shfl_xor(pd[i], off);
        }
    }
    #pragma unroll
    for (int i = 0; i < 4; i++) {
        int gm = bm + (ty << 2) + i;
        if (gm < M) {
            ushort4 o;
            o.x = f2bf(acc[i][0]); o.y = f2bf(acc[i][1]);
            o.z = f2bf(acc[i][2]); o.w = f2bf(acc[i][3]);
            *(ushort4*)(H1b + (long)gm * 256 + bn + (tx << 2)) = o;
            if ((tx & 7) == 0) {
                as1[(gm << 3) + hb] = ps[i];
                ad1[(gm << 3) + hb] = pd[i];
            }
        }
    }
}

// ---------------- CSR build ----------------
__global__ void deg_init_k(int* deg, int Nn)
{
    int i = blockIdx.x * 256 + threadIdx.x;
    if (i < Nn) deg[i] = 1;  // self loop
}
__global__ void deg_count_k(const int* __restrict__ dst, int E, int* deg)
{
    int i = blockIdx.x * 256 + threadIdx.x;
    if (i < E) atomicAdd(&deg[dst[i]], 1);
}
__global__ __launch_bounds__(256) void scan1_k(const int* __restrict__ deg,
                                               int* __restrict__ incl,
                                               int* __restrict__ bsum, int Nn)
{
    __shared__ int sh[256];
    int t = threadIdx.x;
    int base = blockIdx.x * 1024 + t * 4;
    int v0 = (base     < Nn) ? deg[base]     : 0;
    int v1 = (base + 1 < Nn) ? deg[base + 1] : 0;
    int v2 = (base + 2 < Nn) ? deg[base + 2] : 0;
    int v3 = (base + 3 < Nn) ? deg[base + 3] : 0;
    int s0 = v0, s1 = s0 + v1, s2 = s1 + v2, s3 = s2 + v3;
    sh[t] = s3;
    __syncthreads();
    for (int off = 1; off < 256; off <<= 1) {
        int x = (t >= off) ? sh[t - off] : 0;
        __syncthreads();
        sh[t] += x;
        __syncthreads();
    }
    int prev = (t > 0) ? sh[t - 1] : 0;
    if (base     < Nn) incl[base]     = prev + s0;
    if (base + 1 < Nn) incl[base + 1] = prev + s1;
    if (base + 2 < Nn) incl[base + 2] = prev + s2;
    if (base + 3 < Nn) incl[base + 3] = prev + s3;
    if (t == 255) bsum[blockIdx.x] = sh[255];
}
__global__ void scan2_k(const int* __restrict__ bsum, int* __restrict__ bpre, int nb)
{
    int t = threadIdx.x;                // single wave, nb <= 64
    int own = (t < nb) ? bsum[t] : 0;
    int v = own;
    for (int off = 1; off < 64; off <<= 1) {
        int x = __shfl_up(v, off);
        if (t >= off) v += x;
    }
    if (t < nb) bpre[t] = v - own;      // exclusive
}
__global__ void scan3_k(const int* __restrict__ incl, const int* __restrict__ deg,
                        const int* __restrict__ bpre, int* __restrict__ offs,
                        int* __restrict__ cursor, int Nn, int Etot)
{
    int i = blockIdx.x * 256 + threadIdx.x;
    if (i < Nn) {
        int e = bpre[i >> 10] + incl[i] - deg[i];
        offs[i] = e;
        cursor[i] = e;
    }
    if (i == 0) offs[Nn] = Etot;
}
__global__ void scatter_k(const int* __restrict__ src, const int* __restrict__ dst,
                          int E, int Nn, int* cursor, int* __restrict__ srcs)
{
    int i = blockIdx.x * 256 + threadIdx.x;
    if (i < E) {
        int p = atomicAdd(&cursor[dst[i]], 1);
        srcs[p] = src[i];
    } else if (i < E + Nn) {
        int n = i - E;
        int p = atomicAdd(&cursor[n], 1);
        srcs[p] = n;                    // self loop
    }
}

// ---------------- GAT layer 1 aggregate: wave per dst node (bf16 gather) ----------------
__global__ __launch_bounds__(256) void gat1_agg_k(const ushort_t* __restrict__ H1b,
    const float* __restrict__ as1, const float* __restrict__ ad1,
    const int* __restrict__ offs, const int* __restrict__ srcs,
    const float* __restrict__ b1, ushort_t* __restrict__ X1b, int Nn)
{
    int w = (blockIdx.x << 2) + (threadIdx.x >> 6);
    if (w >= Nn) return;
    int lane = threadIdx.x & 63;
    int he = lane & 7, el = lane >> 3;
    int beg = offs[w], end = offs[w + 1];
    float adv = ad1[(w << 3) + he];
    // pass 1: online softmax (max + denom in one sweep)
    float m = -1e30f, d = 0.f;
    for (int j0 = beg; j0 < end; j0 += 8) {
        int j = j0 + el;
        if (j < end) {
            int s = srcs[j];
            float e = lrelu(as1[(s << 3) + he] + adv);
            float nm = fmaxf(m, e);
            d = d * __expf(m - nm) + __expf(e - nm);
            m = nm;
        }
    }
    #pragma unroll
    for (int off = 8; off < 64; off <<= 1) {
        float mo = __shfl_xor(m, off);
        float dd = __shfl_xor(d, off);
        float nm = fmaxf(m, mo);
        d = d * __expf(m - nm) + dd * __expf(mo - nm);
        m = nm;
    }
    float inv = 1.f / d;
    // pass 2: weighted bf16x4 gather-accumulate (8B/lane, 512B/row)
    float4 acc = {0.f, 0.f, 0.f, 0.f};
    int myh = lane >> 3;    // head owning this lane's 4 channels
    for (int j0 = beg; j0 < end; j0 += 8) {
        int j = j0 + el;
        int s = 0; float wv = 0.f;
        if (j < end) {
            s = srcs[j];
            wv = __expf(lrelu(as1[(s << 3) + he] + adv) - m) * inv;
        }
        int ne = min(end - j0, 8);
        int sb[8]; float wb[8];
        #pragma unroll
        for (int e8 = 0; e8 < 8; e8++) {
            sb[e8] = __shfl(s, e8 << 3);
            wb[e8] = __shfl(wv, (e8 << 3) + myh);
        }
        #pragma unroll
        for (int e8 = 0; e8 < 8; e8++) {
            if (e8 < ne) {
                uint2 v = ((const uint2*)(H1b + ((long)sb[e8] << 8)))[lane];
                acc.x += wb[e8] * bf_lo(v.x);
                acc.y += wb[e8] * bf_hi(v.x);
                acc.z += wb[e8] * bf_lo(v.y);
                acc.w += wb[e8] * bf_hi(v.y);
            }
        }
    }
    float4 bb = ((const float4*)b1)[lane];
    float o0 = fmaxf(acc.x + bb.x, 0.f);
    float o1 = fmaxf(acc.y + bb.y, 0.f);
    float o2 = fmaxf(acc.z + bb.z, 0.f);
    float o3 = fmaxf(acc.w + bb.w, 0.f);
    uint2 ov;
    ov.x = (uint_t)f2bf(o0) | ((uint_t)f2bf(o1) << 16);
    ov.y = (uint_t)f2bf(o2) | ((uint_t)f2bf(o3) << 16);
    ((uint2*)(X1b + ((long)w << 8)))[lane] = ov;
}

// ---------------- GEMM2 + alpha2: h2 = x1 @ W2, wave per node (bf16 x1) ----------------
__global__ __launch_bounds__(256) void gemm2_k(const ushort_t* __restrict__ X1b,
    const float* __restrict__ W2, const float* __restrict__ a2s_w,
    const float* __restrict__ a2d_w, float* __restrict__ H2,
    float* __restrict__ as2, float* __restrict__ ad2, int Nn)
{
    __shared__ float Wt[16 * 256];   // transposed: Wt[c][k]
    for (int i = threadIdx.x; i < 16 * 256; i += 256) {
        int c = i >> 8, k = i & 255;
        Wt[i] = W2[(k << 4) + c];
    }
    __syncthreads();
    int w = (blockIdx.x << 2) + (threadIdx.x >> 6);
    if (w >= Nn) return;
    int lane = threadIdx.x & 63;
    int c = lane & 15, kg = lane >> 4;
    const uint2* xr = (const uint2*)(X1b + ((long)w << 8));
    const float* wr = Wt + (c << 8);
    float sum = 0.f;
    #pragma unroll
    for (int t = 0; t < 16; t++) {
        uint2 v = xr[(t << 2) + kg];
        int k = (t << 4) + (kg << 2);
        sum += bf_lo(v.x) * wr[k]     + bf_hi(v.x) * wr[k + 1]
             + bf_lo(v.y) * wr[k + 2] + bf_hi(v.y) * wr[k + 3];
    }
    sum += __shfl_xor(sum, 16);
    sum += __shfl_xor(sum, 32);
    float vs = sum * a2s_w[c];
    float vd = sum * a2d_w[c];
    #pragma unroll
    for (int off = 1; off < 16; off <<= 1) {
        vs += __shfl_xor(vs, off);
        vd += __shfl_xor(vd, off);
    }
    if (kg == 0) {
        H2[(w << 4) + c] = sum;
        if (c == 0) { as2[w] = vs; ad2[w] = vd; }
    }
}

// ---------------- GAT layer 2 aggregate + final softmax ----------------
__global__ __launch_bounds__(256) void gat2_agg_k(const float* __restrict__ H2,
    const float* __restrict__ as2, const float* __restrict__ ad2,
    const int* __restrict__ offs, const int* __restrict__ srcs,
    const float* __restrict__ b2, float* __restrict__ out, int Nn)
{
    int w = (blockIdx.x << 2) + (threadIdx.x >> 6);
    if (w >= Nn) return;
    int lane = threadIdx.x & 63;
    int beg = offs[w], end = offs[w + 1];
    float adv = ad2[w];
    // online max+denom
    float m = -1e30f, d = 0.f;
    for (int j = beg + lane; j < end; j += 64) {
        float e = lrelu(as2[srcs[j]] + adv);
        float nm = fmaxf(m, e);
        d = d * __expf(m - nm) + __expf(e - nm);
        m = nm;
    }
    #pragma unroll
    for (int off = 1; off < 64; off <<= 1) {
        float mo = __shfl_xor(m, off);
        float dd = __shfl_xor(d, off);
        float nm = fmaxf(m, mo);
        d = d * __expf(m - nm) + dd * __expf(mo - nm);
        m = nm;
    }
    float inv = 1.f / d;
    int c = lane & 15, eg = lane >> 4;
    float acc = 0.f;
    for (int j0 = beg; j0 < end; j0 += 4) {
        int j = j0 + eg;
        if (j < end) {
            int s = srcs[j];
            float wv = __expf(lrelu(as2[s] + adv) - m) * inv;
            acc += wv * H2[(s << 4) + c];
        }
    }
    acc += __shfl_xor(acc, 16);
    acc += __shfl_xor(acc, 32);
    float v = acc + b2[c];
    float mx = v;
    #pragma unroll
    for (int off = 1; off < 16; off <<= 1) mx = fmaxf(mx, __shfl_xor(mx, off));
    float ex = __expf(v - mx);
    float se = ex;
    #pragma unroll
    for (int off = 1; off < 16; off <<= 1) se += __shfl_xor(se, off);
    if (eg == 0) out[(w << 4) + c] = ex / se;
}

// ---------------- host launcher ----------------
extern "C" void kernel_launch(void* const* d_in, const int* in_sizes, int n_in,
                              void* d_out, int out_size, void* d_ws, size_t ws_size,
                              hipStream_t stream)
{
    const float* x    = (const float*)d_in[0];
    const int*   ei   = (const int*)d_in[1];
    const float* W1   = (const float*)d_in[2];
    const float* a1s  = (const float*)d_in[3];
    const float* a1d  = (const float*)d_in[4];
    const float* b1   = (const float*)d_in[5];
    const float* W2   = (const float*)d_in[6];
    const float* a2s  = (const float*)d_in[7];
    const float* a2d  = (const float*)d_in[8];
    const float* b2   = (const float*)d_in[9];
    float* out = (float*)d_out;

    int N = in_sizes[0] / HID;
    int E = in_sizes[1] / 2;
    int Etot = E + N;
    const int* src = ei;
    const int* dst = ei + E;

    char* p = (char*)d_ws;
    auto alloc = [&](size_t bytes) {
        void* r = (void*)p;
        p += (bytes + 255) & ~(size_t)255;
        return r;
    };
    ushort_t* h1b  = (ushort_t*)alloc((size_t)N * 256 * 2);
    ushort_t* x1b  = (ushort_t*)alloc((size_t)N * 256 * 2);
    float* h2      = (float*)alloc((size_t)N * 16 * 4);
    float* as1     = (float*)alloc((size_t)N * 8 * 4);
    float* ad1     = (float*)alloc((size_t)N * 8 * 4);
    float* as2v    = (float*)alloc((size_t)N * 4);
    float* ad2v    = (float*)alloc((size_t)N * 4);
    int*   deg     = (int*)alloc((size_t)N * 4);
    int*   incl    = (int*)alloc((size_t)N * 4);
    int*   offs    = (int*)alloc((size_t)(N + 1) * 4);
    int*   cursor  = (int*)alloc((size_t)N * 4);
    int*   bsum    = (int*)alloc(256 * 4);
    int*   bpre    = (int*)alloc(256 * 4);
    int*   srcs    = (int*)alloc((size_t)Etot * 4);

    int nb = (N + 1023) / 1024;

    // GEMM1 (+ fused alpha1): col-tile fastest for X-tile L2/L3 reuse
    dim3 g1(4, (N + 63) / 64);
    hipLaunchKernelGGL(gemm1_k, g1, dim3(256), 0, stream,
                       x, W1, a1s, a1d, h1b, as1, ad1, N);
    // CSR build
    hipLaunchKernelGGL(deg_init_k, dim3((N + 255) / 256), dim3(256), 0, stream, deg, N);
    hipLaunchKernelGGL(deg_count_k, dim3((E + 255) / 256), dim3(256), 0, stream, dst, E, deg);
    hipLaunchKernelGGL(scan1_k, dim3(nb), dim3(256), 0, stream, deg, incl, bsum, N);
    hipLaunchKernelGGL(scan2_k, dim3(1), dim3(64), 0, stream, bsum, bpre, nb);
    hipLaunchKernelGGL(scan3_k, dim3((N + 255) / 256), dim3(256), 0, stream,
                       incl, deg, bpre, offs, cursor, N, Etot);
    hipLaunchKernelGGL(scatter_k, dim3((Etot + 255) / 256), dim3(256), 0, stream,
                       src, dst, E, N, cursor, srcs);
    // layer 1 aggregate
    hipLaunchKernelGGL(gat1_agg_k, dim3((N + 3) / 4), dim3(256), 0, stream,
                       h1b, as1, ad1, offs, srcs, b1, x1b, N);
    // layer 2
    hipLaunchKernelGGL(gemm2_k, dim3((N + 3) / 4), dim3(256), 0, stream,
                       x1b, W2, a2s, a2d, h2, as2v, ad2v, N);
    hipLaunchKernelGGL(gat2_agg_k, dim3((N + 3) / 4), dim3(256), 0, stream,
                       h2, as2v, ad2v, offs, srcs, b2, out, N);
}

// Round 4
// 352.912 us; speedup vs baseline: 1.2725x; 1.0694x over previous
//
#include <hip/hip_runtime.h>
#include <hip/hip_bf16.h>

#define HID 256
#define H1H 8
#define C1 32
#define C2 16
#define NEG 0.2f

typedef unsigned short ushort_t;
typedef unsigned int uint_t;
typedef __attribute__((ext_vector_type(8))) short short8;
typedef __attribute__((ext_vector_type(4))) float f32x4;

__device__ __forceinline__ float lrelu(float t){ return (t >= 0.f) ? t : NEG * t; }
__device__ __forceinline__ ushort_t f2bf(float f){
    uint_t u = __float_as_uint(f);
    u = (u + 0x7fffu + ((u >> 16) & 1u)) >> 16;   // RNE
    return (ushort_t)u;
}
__device__ __forceinline__ float bf_lo(uint_t p){ return __uint_as_float(p << 16); }
__device__ __forceinline__ float bf_hi(uint_t p){ return __uint_as_float(p & 0xffff0000u); }

// ---------------- prep: W1t[n][k] = bf16(W1[k][n]) ----------------
__global__ __launch_bounds__(256) void w1prep_k(const float* __restrict__ W1,
                                                ushort_t* __restrict__ W1t)
{
    __shared__ ushort_t sh[32][33];
    int bx = blockIdx.x & 7, by = blockIdx.x >> 3;   // k-tile, n-tile
    int tx = threadIdx.x & 31, ty = threadIdx.x >> 5; // 32 x 8
    #pragma unroll
    for (int i = 0; i < 32; i += 8)
        sh[ty + i][tx] = f2bf(W1[(long)(bx * 32 + ty + i) * 256 + by * 32 + tx]);
    __syncthreads();
    #pragma unroll
    for (int i = 0; i < 32; i += 8)
        W1t[(long)(by * 32 + ty + i) * 256 + bx * 32 + tx] = sh[tx][ty + i];
}

// ---------------- GEMM1 (MFMA): h1b = bf16( relu(x) @ W1 ) ----------------
// grid: (2 col-tiles of 128, rowTiles of 128), 256 thr = 4 waves (2x2 of 64x64)
__global__ __launch_bounds__(256) void gemm1_k(const float* __restrict__ X,
                                               const ushort_t* __restrict__ W1t,
                                               ushort_t* __restrict__ H1b, int M)
{
    __shared__ ushort_t A2[4][128][8];   // [kg][row][8k] bf16
    __shared__ ushort_t B2[4][128][8];   // [kg][col][8k] bf16
    int tid = threadIdx.x;
    int bm = blockIdx.y * 128, bn = blockIdx.x * 128;
    int wid = tid >> 6, lane = tid & 63;
    int wr = wid >> 1, wc = wid & 1;
    int lg = lane >> 4, lm = lane & 15;

    f32x4 acc[4][4];
    #pragma unroll
    for (int m = 0; m < 4; m++)
        #pragma unroll
        for (int n = 0; n < 4; n++) acc[m][n] = (f32x4){0.f, 0.f, 0.f, 0.f};

    int tq = tid & 7, trow = tid >> 3;   // A staging: row, 4k-quad
    int bkc = tid & 3, brow = tid >> 2;  // B staging: col-row, 8k-chunk

    for (int k0 = 0; k0 < 256; k0 += 32) {
        __syncthreads();
        // stage A: fp32 -> relu -> bf16
        #pragma unroll
        for (int i = 0; i < 4; i++) {
            int row = trow + (i << 5);
            int gm = bm + row;
            float4 xv = {0.f, 0.f, 0.f, 0.f};
            if (gm < M) xv = *(const float4*)(X + (long)gm * 256 + k0 + (tq << 2));
            uint2 pk;
            pk.x = (uint_t)f2bf(fmaxf(xv.x, 0.f)) | ((uint_t)f2bf(fmaxf(xv.y, 0.f)) << 16);
            pk.y = (uint_t)f2bf(fmaxf(xv.z, 0.f)) | ((uint_t)f2bf(fmaxf(xv.w, 0.f)) << 16);
            *(uint2*)&A2[tq >> 1][row][(tq & 1) << 2] = pk;
        }
        // stage B: already bf16, N-major
        #pragma unroll
        for (int i = 0; i < 2; i++) {
            int row = brow + (i << 6);
            uint4 wv = *(const uint4*)(W1t + (long)(bn + row) * 256 + k0 + (bkc << 3));
            *(uint4*)&B2[bkc][row][0] = wv;
        }
        __syncthreads();
        // fragments + MFMA
        short8 af[4], bf[4];
        #pragma unroll
        for (int m = 0; m < 4; m++)
            af[m] = *(const short8*)&A2[lg][wr * 64 + m * 16 + lm][0];
        #pragma unroll
        for (int n = 0; n < 4; n++)
            bf[n] = *(const short8*)&B2[lg][wc * 64 + n * 16 + lm][0];
        #pragma unroll
        for (int m = 0; m < 4; m++)
            #pragma unroll
            for (int n = 0; n < 4; n++)
                acc[m][n] = __builtin_amdgcn_mfma_f32_16x16x32_bf16(af[m], bf[n], acc[m][n], 0, 0, 0);
    }
    // epilogue: D[row=(lane>>4)*4+r][col=lane&15]
    #pragma unroll
    for (int m = 0; m < 4; m++) {
        #pragma unroll
        for (int r = 0; r < 4; r++) {
            int gm = bm + wr * 64 + m * 16 + lg * 4 + r;
            if (gm < M) {
                long base = (long)gm * 256 + bn + wc * 64 + lm;
                #pragma unroll
                for (int n = 0; n < 4; n++)
                    H1b[base + n * 16] = f2bf(acc[m][n][r]);
            }
        }
    }
}

// ---------------- alpha1: per (n,h) dot of bf16 h1 row with a_src/a_dst ----------------
__global__ __launch_bounds__(256) void alpha1_k(const ushort_t* __restrict__ H1b,
                                                const float* __restrict__ a1s,
                                                const float* __restrict__ a1d,
                                                float* __restrict__ as1,
                                                float* __restrict__ ad1, int Nn)
{
    int i = blockIdx.x * 256 + threadIdx.x;
    if (i >= Nn * H1H) return;
    int h = i & 7;
    const uint4* row = (const uint4*)(H1b + (long)i * C1);
    const float* av = a1s + h * C1;
    const float* dv = a1d + h * C1;
    float ss = 0.f, sd = 0.f;
    #pragma unroll
    for (int q = 0; q < 4; q++) {
        uint4 v = row[q];
        float x0 = bf_lo(v.x), x1 = bf_hi(v.x), x2 = bf_lo(v.y), x3 = bf_hi(v.y);
        float x4 = bf_lo(v.z), x5 = bf_hi(v.z), x6 = bf_lo(v.w), x7 = bf_hi(v.w);
        int k = q << 3;
        ss += x0*av[k] + x1*av[k+1] + x2*av[k+2] + x3*av[k+3]
            + x4*av[k+4] + x5*av[k+5] + x6*av[k+6] + x7*av[k+7];
        sd += x0*dv[k] + x1*dv[k+1] + x2*dv[k+2] + x3*dv[k+3]
            + x4*dv[k+4] + x5*dv[k+5] + x6*dv[k+6] + x7*dv[k+7];
    }
    as1[i] = ss; ad1[i] = sd;
}

// ---------------- CSR build ----------------
__global__ void deg_init_k(int* deg, int Nn)
{
    int i = blockIdx.x * 256 + threadIdx.x;
    if (i < Nn) deg[i] = 1;  // self loop
}
__global__ void deg_count_k(const int* __restrict__ dst, int E, int* deg)
{
    int i = blockIdx.x * 256 + threadIdx.x;
    if (i < E) atomicAdd(&deg[dst[i]], 1);
}
__global__ __launch_bounds__(256) void scan1_k(const int* __restrict__ deg,
                                               int* __restrict__ incl,
                                               int* __restrict__ bsum, int Nn)
{
    __shared__ int sh[256];
    int t = threadIdx.x;
    int base = blockIdx.x * 1024 + t * 4;
    int v0 = (base     < Nn) ? deg[base]     : 0;
    int v1 = (base + 1 < Nn) ? deg[base + 1] : 0;
    int v2 = (base + 2 < Nn) ? deg[base + 2] : 0;
    int v3 = (base + 3 < Nn) ? deg[base + 3] : 0;
    int s0 = v0, s1 = s0 + v1, s2 = s1 + v2, s3 = s2 + v3;
    sh[t] = s3;
    __syncthreads();
    for (int off = 1; off < 256; off <<= 1) {
        int x = (t >= off) ? sh[t - off] : 0;
        __syncthreads();
        sh[t] += x;
        __syncthreads();
    }
    int prev = (t > 0) ? sh[t - 1] : 0;
    if (base     < Nn) incl[base]     = prev + s0;
    if (base + 1 < Nn) incl[base + 1] = prev + s1;
    if (base + 2 < Nn) incl[base + 2] = prev + s2;
    if (base + 3 < Nn) incl[base + 3] = prev + s3;
    if (t == 255) bsum[blockIdx.x] = sh[255];
}
__global__ void scan2_k(const int* __restrict__ bsum, int* __restrict__ bpre, int nb)
{
    int t = threadIdx.x;                // single wave, nb <= 64
    int own = (t < nb) ? bsum[t] : 0;
    int v = own;
    for (int off = 1; off < 64; off <<= 1) {
        int x = __shfl_up(v, off);
        if (t >= off) v += x;
    }
    if (t < nb) bpre[t] = v - own;      // exclusive
}
__global__ void scan3_k(const int* __restrict__ incl, const int* __restrict__ deg,
                        const int* __restrict__ bpre, int* __restrict__ offs,
                        int* __restrict__ cursor, int Nn, int Etot)
{
    int i = blockIdx.x * 256 + threadIdx.x;
    if (i < Nn) {
        int e = bpre[i >> 10] + incl[i] - deg[i];
        offs[i] = e;
        cursor[i] = e;
    }
    if (i == 0) offs[Nn] = Etot;
}
__global__ void scatter_k(const int* __restrict__ src, const int* __restrict__ dst,
                          int E, int Nn, int* cursor, int* __restrict__ srcs)
{
    int i = blockIdx.x * 256 + threadIdx.x;
    if (i < E) {
        int p = atomicAdd(&cursor[dst[i]], 1);
        srcs[p] = src[i];
    } else if (i < E + Nn) {
        int n = i - E;
        int p = atomicAdd(&cursor[n], 1);
        srcs[p] = n;                    // self loop
    }
}

// ---------------- GAT layer 1 aggregate: wave per dst node (bf16 gather) ----------------
__global__ __launch_bounds__(256) void gat1_agg_k(const ushort_t* __restrict__ H1b,
    const float* __restrict__ as1, const float* __restrict__ ad1,
    const int* __restrict__ offs, const int* __restrict__ srcs,
    const float* __restrict__ b1, ushort_t* __restrict__ X1b, int Nn)
{
    int w = (blockIdx.x << 2) + (threadIdx.x >> 6);
    if (w >= Nn) return;
    int lane = threadIdx.x & 63;
    int he = lane & 7, el = lane >> 3;
    int beg = offs[w], end = offs[w + 1];
    float adv = ad1[(w << 3) + he];
    // pass 1: online softmax (max + denom in one sweep)
    float m = -1e30f, d = 0.f;
    for (int j0 = beg; j0 < end; j0 += 8) {
        int j = j0 + el;
        if (j < end) {
            int s = srcs[j];
            float e = lrelu(as1[(s << 3) + he] + adv);
            float nm = fmaxf(m, e);
            d = d * __expf(m - nm) + __expf(e - nm);
            m = nm;
        }
    }
    #pragma unroll
    for (int off = 8; off < 64; off <<= 1) {
        float mo = __shfl_xor(m, off);
        float dd = __shfl_xor(d, off);
        float nm = fmaxf(m, mo);
        d = d * __expf(m - nm) + dd * __expf(mo - nm);
        m = nm;
    }
    float inv = 1.f / d;
    // pass 2: weighted bf16x4 gather-accumulate (8B/lane, 512B/row)
    float4 acc = {0.f, 0.f, 0.f, 0.f};
    int myh = lane >> 3;    // head owning this lane's 4 channels
    for (int j0 = beg; j0 < end; j0 += 8) {
        int j = j0 + el;
        int s = 0; float wv = 0.f;
        if (j < end) {
            s = srcs[j];
            wv = __expf(lrelu(as1[(s << 3) + he] + adv) - m) * inv;
        }
        int ne = min(end - j0, 8);
        int sb[8]; float wb[8];
        #pragma unroll
        for (int e8 = 0; e8 < 8; e8++) {
            sb[e8] = __shfl(s, e8 << 3);
            wb[e8] = __shfl(wv, (e8 << 3) + myh);
        }
        #pragma unroll
        for (int e8 = 0; e8 < 8; e8++) {
            if (e8 < ne) {
                uint2 v = ((const uint2*)(H1b + ((long)sb[e8] << 8)))[lane];
                acc.x += wb[e8] * bf_lo(v.x);
                acc.y += wb[e8] * bf_hi(v.x);
                acc.z += wb[e8] * bf_lo(v.y);
                acc.w += wb[e8] * bf_hi(v.y);
            }
        }
    }
    float4 bb = ((const float4*)b1)[lane];
    float o0 = fmaxf(acc.x + bb.x, 0.f);
    float o1 = fmaxf(acc.y + bb.y, 0.f);
    float o2 = fmaxf(acc.z + bb.z, 0.f);
    float o3 = fmaxf(acc.w + bb.w, 0.f);
    uint2 ov;
    ov.x = (uint_t)f2bf(o0) | ((uint_t)f2bf(o1) << 16);
    ov.y = (uint_t)f2bf(o2) | ((uint_t)f2bf(o3) << 16);
    ((uint2*)(X1b + ((long)w << 8)))[lane] = ov;
}

// ---------------- GEMM2 + alpha2: h2 = x1 @ W2, wave per node (bf16 x1) ----------------
__global__ __launch_bounds__(256) void gemm2_k(const ushort_t* __restrict__ X1b,
    const float* __restrict__ W2, const float* __restrict__ a2s_w,
    const float* __restrict__ a2d_w, float* __restrict__ H2,
    float* __restrict__ as2, float* __restrict__ ad2, int Nn)
{
    __shared__ float Wt[16 * 256];   // transposed: Wt[c][k]
    for (int i = threadIdx.x; i < 16 * 256; i += 256) {
        int c = i >> 8, k = i & 255;
        Wt[i] = W2[(k << 4) + c];
    }
    __syncthreads();
    int w = (blockIdx.x << 2) + (threadIdx.x >> 6);
    if (w >= Nn) return;
    int lane = threadIdx.x & 63;
    int c = lane & 15, kg = lane >> 4;
    const uint2* xr = (const uint2*)(X1b + ((long)w << 8));
    const float* wr = Wt + (c << 8);
    float sum = 0.f;
    #pragma unroll
    for (int t = 0; t < 16; t++) {
        uint2 v = xr[(t << 2) + kg];
        int k = (t << 4) + (kg << 2);
        sum += bf_lo(v.x) * wr[k]     + bf_hi(v.x) * wr[k + 1]
             + bf_lo(v.y) * wr[k + 2] + bf_hi(v.y) * wr[k + 3];
    }
    sum += __shfl_xor(sum, 16);
    sum += __shfl_xor(sum, 32);
    float vs = sum * a2s_w[c];
    float vd = sum * a2d_w[c];
    #pragma unroll
    for (int off = 1; off < 16; off <<= 1) {
        vs += __shfl_xor(vs, off);
        vd += __shfl_xor(vd, off);
    }
    if (kg == 0) {
        H2[(w << 4) + c] = sum;
        if (c == 0) { as2[w] = vs; ad2[w] = vd; }
    }
}

// ---------------- GAT layer 2 aggregate + final softmax ----------------
__global__ __launch_bounds__(256) void gat2_agg_k(const float* __restrict__ H2,
    const float* __restrict__ as2, const float* __restrict__ ad2,
    const int* __restrict__ offs, const int* __restrict__ srcs,
    const float* __restrict__ b2, float* __restrict__ out, int Nn)
{
    int w = (blockIdx.x << 2) + (threadIdx.x >> 6);
    if (w >= Nn) return;
    int lane = threadIdx.x & 63;
    int beg = offs[w], end = offs[w + 1];
    float adv = ad2[w];
    // online max+denom
    float m = -1e30f, d = 0.f;
    for (int j = beg + lane; j < end; j += 64) {
        float e = lrelu(as2[srcs[j]] + adv);
        float nm = fmaxf(m, e);
        d = d * __expf(m - nm) + __expf(e - nm);
        m = nm;
    }
    #pragma unroll
    for (int off = 1; off < 64; off <<= 1) {
        float mo = __shfl_xor(m, off);
        float dd = __shfl_xor(d, off);
        float nm = fmaxf(m, mo);
        d = d * __expf(m - nm) + dd * __expf(mo - nm);
        m = nm;
    }
    float inv = 1.f / d;
    int c = lane & 15, eg = lane >> 4;
    float acc = 0.f;
    for (int j0 = beg; j0 < end; j0 += 4) {
        int j = j0 + eg;
        if (j < end) {
            int s = srcs[j];
            float wv = __expf(lrelu(as2[s] + adv) - m) * inv;
            acc += wv * H2[(s << 4) + c];
        }
    }
    acc += __shfl_xor(acc, 16);
    acc += __shfl_xor(acc, 32);
    float v = acc + b2[c];
    float mx = v;
    #pragma unroll
    for (int off = 1; off < 16; off <<= 1) mx = fmaxf(mx, __shfl_xor(mx, off));
    float ex = __expf(v - mx);
    float se = ex;
    #pragma unroll
    for (int off = 1; off < 16; off <<= 1) se += __shfl_xor(se, off);
    if (eg == 0) out[(w << 4) + c] = ex / se;
}

// ---------------- host launcher ----------------
extern "C" void kernel_launch(void* const* d_in, const int* in_sizes, int n_in,
                              void* d_out, int out_size, void* d_ws, size_t ws_size,
                              hipStream_t stream)
{
    const float* x    = (const float*)d_in[0];
    const int*   ei   = (const int*)d_in[1];
    const float* W1   = (const float*)d_in[2];
    const float* a1s  = (const float*)d_in[3];
    const float* a1d  = (const float*)d_in[4];
    const float* b1   = (const float*)d_in[5];
    const float* W2   = (const float*)d_in[6];
    const float* a2s  = (const float*)d_in[7];
    const float* a2d  = (const float*)d_in[8];
    const float* b2   = (const float*)d_in[9];
    float* out = (float*)d_out;

    int N = in_sizes[0] / HID;
    int E = in_sizes[1] / 2;
    int Etot = E + N;
    const int* src = ei;
    const int* dst = ei + E;

    char* p = (char*)d_ws;
    auto alloc = [&](size_t bytes) {
        void* r = (void*)p;
        p += (bytes + 255) & ~(size_t)255;
        return r;
    };
    ushort_t* h1b  = (ushort_t*)alloc((size_t)N * 256 * 2);
    ushort_t* x1b  = (ushort_t*)alloc((size_t)N * 256 * 2);
    ushort_t* w1t  = (ushort_t*)alloc((size_t)256 * 256 * 2);
    float* h2      = (float*)alloc((size_t)N * 16 * 4);
    float* as1     = (float*)alloc((size_t)N * 8 * 4);
    float* ad1     = (float*)alloc((size_t)N * 8 * 4);
    float* as2v    = (float*)alloc((size_t)N * 4);
    float* ad2v    = (float*)alloc((size_t)N * 4);
    int*   deg     = (int*)alloc((size_t)N * 4);
    int*   incl    = (int*)alloc((size_t)N * 4);
    int*   offs    = (int*)alloc((size_t)(N + 1) * 4);
    int*   cursor  = (int*)alloc((size_t)N * 4);
    int*   bsum    = (int*)alloc(256 * 4);
    int*   bpre    = (int*)alloc(256 * 4);
    int*   srcs    = (int*)alloc((size_t)Etot * 4);

    int nb = (N + 1023) / 1024;

    // prep + GEMM1 (MFMA) + alpha1
    hipLaunchKernelGGL(w1prep_k, dim3(64), dim3(256), 0, stream, W1, w1t);
    dim3 g1(2, (N + 127) / 128);
    hipLaunchKernelGGL(gemm1_k, g1, dim3(256), 0, stream, x, w1t, h1b, N);
    hipLaunchKernelGGL(alpha1_k, dim3((N * 8 + 255) / 256), dim3(256), 0, stream,
                       h1b, a1s, a1d, as1, ad1, N);
    // CSR build
    hipLaunchKernelGGL(deg_init_k, dim3((N + 255) / 256), dim3(256), 0, stream, deg, N);
    hipLaunchKernelGGL(deg_count_k, dim3((E + 255) / 256), dim3(256), 0, stream, dst, E, deg);
    hipLaunchKernelGGL(scan1_k, dim3(nb), dim3(256), 0, stream, deg, incl, bsum, N);
    hipLaunchKernelGGL(scan2_k, dim3(1), dim3(64), 0, stream, bsum, bpre, nb);
    hipLaunchKernelGGL(scan3_k, dim3((N + 255) / 256), dim3(256), 0, stream,
                       incl, deg, bpre, offs, cursor, N, Etot);
    hipLaunchKernelGGL(scatter_k, dim3((Etot + 255) / 256), dim3(256), 0, stream,
                       src, dst, E, N, cursor, srcs);
    // layer 1 aggregate
    hipLaunchKernelGGL(gat1_agg_k, dim3((N + 3) / 4), dim3(256), 0, stream,
                       h1b, as1, ad1, offs, srcs, b1, x1b, N);
    // layer 2
    hipLaunchKernelGGL(gemm2_k, dim3((N + 3) / 4), dim3(256), 0, stream,
                       x1b, W2, a2s, a2d, h2, as2v, ad2v, N);
    hipLaunchKernelGGL(gat2_agg_k, dim3((N + 3) / 4), dim3(256), 0, stream,
                       h2, as2v, ad2v, offs, srcs, b2, out, N);
}